// Round 2
// baseline (2094.741 us; speedup 1.0000x reference)
//
#include <hip/hip_runtime.h>
#include <cstdint>
#include <cstddef>

typedef uint32_t u32;
typedef uint64_t u64;

#define NB 16
#define NC 4000
#define NCPAD 4096
#define POSTN 1000
#define PREN 1000

__constant__ int c_N[4]    = {120000, 30000, 7500, 1875};
__constant__ int c_OFF[4]  = {0, 120000, 150000, 157500};
__constant__ int c_HW[4]   = {40000, 10000, 2500, 625};
__constant__ int c_W[4]    = {200, 100, 50, 25};
__constant__ int c_BASE[4] = {0, 1000, 2000, 3000};

__device__ __forceinline__ u32 ord_bits(float f) {
  u32 u = __float_as_uint(f);
  return (u & 0x80000000u) ? ~u : (u | 0x80000000u);
}
__device__ __forceinline__ float inv_ord(u32 o) {
  u32 bits = (o & 0x80000000u) ? (o ^ 0x80000000u) : ~o;
  return __uint_as_float(bits);
}
__device__ __forceinline__ u64 make_key(float f, u32 gid) {
  return ((u64)ord_bits(f) << 32) | (u64)(u32)(~gid);
}

struct DecBox { float x1, y1, x2, y2; int lvl; bool valid; };

__device__ DecBox decode_box(u32 gid, int b,
    const float* __restrict__ reg0, const float* __restrict__ reg1,
    const float* __restrict__ reg2, const float* __restrict__ reg3,
    const float* __restrict__ anchors) {
  int lvl = (gid < 120000u) ? 0 : (gid < 150000u) ? 1 : (gid < 157500u) ? 2 : 3;
  int local = (int)gid - c_OFF[lvl];
  int a = local % 3;
  int cell = local / 3;
  int w = c_W[lvl];
  int hw = c_HW[lvl];
  int y = cell / w;
  int x = cell - y * w;
  const float* reg = (lvl == 0) ? reg0 : (lvl == 1) ? reg1 : (lvl == 2) ? reg2 : reg3;
  size_t base = ((size_t)(b * 12 + a * 4) * (size_t)w + (size_t)y) * (size_t)w + (size_t)x;
  const float CLIPV = 4.135166556742356f; // log(1000/16) as f32
  float dx = reg[base];
  float dy = reg[base + (size_t)hw];
  float dwv = fminf(reg[base + 2 * (size_t)hw], CLIPV);
  float dhv = fminf(reg[base + 3 * (size_t)hw], CLIPV);
  float a0 = anchors[(size_t)gid * 4 + 0];
  float a1 = anchors[(size_t)gid * 4 + 1];
  float a2 = anchors[(size_t)gid * 4 + 2];
  float a3 = anchors[(size_t)gid * 4 + 3];
  float wa = __fsub_rn(a2, a0);
  float ha = __fsub_rn(a3, a1);
  float cxa = __fadd_rn(a0, __fmul_rn(0.5f, wa));
  float cya = __fadd_rn(a1, __fmul_rn(0.5f, ha));
  float pcx = __fadd_rn(__fmul_rn(dx, wa), cxa);
  float pcy = __fadd_rn(__fmul_rn(dy, ha), cya);
  float pw = __fmul_rn(expf(dwv), wa);
  float ph = __fmul_rn(expf(dhv), ha);
  float x1 = __fsub_rn(pcx, __fmul_rn(0.5f, pw));
  float y1 = __fsub_rn(pcy, __fmul_rn(0.5f, ph));
  float x2 = __fadd_rn(pcx, __fmul_rn(0.5f, pw));
  float y2 = __fadd_rn(pcy, __fmul_rn(0.5f, ph));
  x1 = fminf(fmaxf(x1, 0.0f), 800.0f);
  y1 = fminf(fmaxf(y1, 0.0f), 800.0f);
  x2 = fminf(fmaxf(x2, 0.0f), 800.0f);
  y2 = fminf(fmaxf(y2, 0.0f), 800.0f);
  DecBox r;
  r.x1 = x1; r.y1 = y1; r.x2 = x2; r.y2 = y2; r.lvl = lvl;
  r.valid = (__fsub_rn(x2, x1) >= 1.0f) && (__fsub_rn(y2, y1) >= 1.0f);
  return r;
}

// ---------------- K0: zero outputs / counters / candidate keys ----------------
__global__ void k_zero(float* __restrict__ out, u32* __restrict__ counters,
                       u64* __restrict__ cand_key) {
  int i = blockIdx.x * blockDim.x + threadIdx.x;
  if (i < NB * POSTN * 5) out[i] = 0.0f;          // 80000 floats
  if (i < NB * 4) counters[i] = 0u;
  if (i < NB * NCPAD) cand_key[i] = 0ull;
}

// ---------------- K1: exact per-(image,level) radix-select of k-th key --------
__global__ __launch_bounds__(1024) void k_select(
    const float* __restrict__ cls0, const float* __restrict__ cls1,
    const float* __restrict__ cls2, const float* __restrict__ cls3,
    u64* __restrict__ kth) {
  int task = blockIdx.x;         // 0..63
  int b = task & 15;
  int lvl = task >> 4;           // 0..3
  const float* cls = (lvl == 0) ? cls0 : (lvl == 1) ? cls1 : (lvl == 2) ? cls2 : cls3;
  int n = c_N[lvl], hw = c_HW[lvl], off = c_OFF[lvl];
  const float* cp = cls + (size_t)b * (size_t)n;
  __shared__ u32 hist[256];
  __shared__ u64 sh_pval;
  __shared__ u32 sh_kneed;
  int tid = threadIdx.x;
  if (tid == 0) { sh_pval = 0ull; sh_kneed = PREN; }
  u64 pmask = 0ull;
  __syncthreads();
  for (int pass = 7; pass >= 0; --pass) {
    int shift = pass * 8;
    __syncthreads();
    if (tid < 256) hist[tid] = 0u;
    __syncthreads();
    u64 pval = sh_pval;
    for (int e = tid; e < n; e += 1024) {
      float f = cp[e];
      int a = e / hw;
      int cell = e - a * hw;
      u32 gid = (u32)(off + cell * 3 + a);
      u64 key = make_key(f, gid);
      if ((key & pmask) == pval)
        atomicAdd(&hist[(u32)(key >> shift) & 255u], 1u);
    }
    __syncthreads();
    if (tid == 0) {
      u32 kneed = sh_kneed;
      u32 acc = 0;
      for (int bq = 255; bq >= 0; --bq) {
        u32 c = hist[bq];
        if (acc + c >= kneed) {
          sh_pval = pval | ((u64)(u32)bq << shift);
          sh_kneed = kneed - acc;
          break;
        }
        acc += c;
      }
    }
    pmask |= (0xFFull << shift);
    __syncthreads();
  }
  if (tid == 0) kth[b * 4 + lvl] = sh_pval;
}

// ---------------- K2: gather selected candidates, build sort keys -------------
__global__ void k_gather(
    const float* __restrict__ cls0, const float* __restrict__ cls1,
    const float* __restrict__ cls2, const float* __restrict__ cls3,
    const float* __restrict__ reg0, const float* __restrict__ reg1,
    const float* __restrict__ reg2, const float* __restrict__ reg3,
    const float* __restrict__ anchors, const u64* __restrict__ kth,
    u32* __restrict__ counters, u64* __restrict__ cand_key) {
  int e = blockIdx.x * blockDim.x + threadIdx.x;
  const int S1 = 1920000, S2 = 2400000, S3 = 2520000, S4 = 2550000;
  if (e >= S4) return;
  int l, r;
  if (e < S1)      { l = 0; r = e; }
  else if (e < S2) { l = 1; r = e - S1; }
  else if (e < S3) { l = 2; r = e - S2; }
  else             { l = 3; r = e - S3; }
  int n = c_N[l], hw = c_HW[l];
  int b = r / n;
  int m = r - b * n;        // memory order within (a, y, x)
  int a = m / hw;
  int cell = m - a * hw;
  u32 gid = (u32)(c_OFF[l] + cell * 3 + a);
  const float* cls = (l == 0) ? cls0 : (l == 1) ? cls1 : (l == 2) ? cls2 : cls3;
  float f = cls[(size_t)b * (size_t)n + (size_t)m];
  u64 key = make_key(f, gid);
  bool sel = (key >= kth[b * 4 + l]);
  if (sel) {
    DecBox bx = decode_box(gid, b, reg0, reg1, reg2, reg3, anchors);
    u64 skey = bx.valid ? key : (key & 0xFFFFFFFFull); // invalid sorts after all valid
    u32 slot = atomicAdd(&counters[b * 4 + l], 1u);
    if (slot < (u32)PREN)
      cand_key[(size_t)b * NCPAD + (size_t)(c_BASE[l] + (int)slot)] = skey;
  }
}

// ---------------- K3: per-image bitonic sort (desc) + decode payloads ---------
__global__ __launch_bounds__(1024) void k_sort_decode(
    const u64* __restrict__ cand_key,
    const float* __restrict__ reg0, const float* __restrict__ reg1,
    const float* __restrict__ reg2, const float* __restrict__ reg3,
    const float* __restrict__ anchors,
    float4* __restrict__ sbox, float4* __restrict__ boffA,
    float* __restrict__ area, float* __restrict__ score,
    u64* __restrict__ validmask) {
  int b = blockIdx.x;
  int tid = threadIdx.x;
  __shared__ u64 sk[NCPAD];
  for (int p = tid; p < NCPAD; p += 1024) sk[p] = cand_key[(size_t)b * NCPAD + p];
  __syncthreads();
  for (u32 k = 2; k <= NCPAD; k <<= 1) {
    for (u32 j = k >> 1; j > 0; j >>= 1) {
      for (u32 t = tid; t < NCPAD / 2; t += 1024) {
        u32 i = 2u * t - (t & (j - 1u));
        u32 l2 = i | j;
        u64 av = sk[i], bv = sk[l2];
        bool up = ((i & k) == 0u);
        if (up ? (av < bv) : (av > bv)) { sk[i] = bv; sk[l2] = av; }
      }
      __syncthreads();
    }
  }
  for (int c = 0; c < 4; ++c) {
    int p = c * 1024 + tid;
    u64 key = sk[p];
    float4 bx4 = make_float4(0.f, 0.f, 0.f, 0.f);
    float4 bo4 = make_float4(0.f, 0.f, 0.f, 0.f);
    float ar = 0.f, sc = 0.f;
    bool vflag = false;
    if (key != 0ull) {
      u32 gid = ~((u32)key);
      vflag = (key >> 32) != 0ull;
      DecBox bx = decode_box(gid, b, reg0, reg1, reg2, reg3, anchors);
      bx4 = make_float4(bx.x1, bx.y1, bx.x2, bx.y2);
      float offv = __fmul_rn((float)bx.lvl, 801.0f);
      bo4 = make_float4(__fadd_rn(bx.x1, offv), __fadd_rn(bx.y1, offv),
                        __fadd_rn(bx.x2, offv), __fadd_rn(bx.y2, offv));
      ar = __fmul_rn(__fsub_rn(bo4.z, bo4.x), __fsub_rn(bo4.w, bo4.y));
      if (vflag) {
        float logit = inv_ord((u32)(key >> 32));
        sc = 1.0f / (1.0f + expf(-logit));
      }
    }
    size_t gi = (size_t)b * NCPAD + (size_t)p;
    sbox[gi] = bx4;
    boffA[gi] = bo4;
    area[gi] = ar;
    score[gi] = sc;
    u64 bal = __ballot(vflag ? 1 : 0);
    if ((tid & 63) == 0) validmask[b * 64 + (p >> 6)] = bal;
  }
}

// ---------------- K4: IoU suppression bitmask matrix --------------------------
#define RPB 16
__global__ __launch_bounds__(256) void k_mask(
    const float4* __restrict__ boffA, const float* __restrict__ area,
    u64* __restrict__ mask) {
  int bg = blockIdx.x;
  int b = bg / 250;
  int g = bg - b * 250;
  int row0 = g * RPB;
  int tid = threadIdx.x;
  int wave = tid >> 6;
  int lane = tid & 63;
  __shared__ float4 rb[RPB];
  __shared__ float ra[RPB];
  if (tid < RPB) {
    int rr = row0 + tid;
    int rc = (rr < NCPAD) ? rr : (NCPAD - 1);
    rb[tid] = boffA[(size_t)b * NCPAD + rc];
    ra[tid] = area[(size_t)b * NCPAD + rc];
  }
  __syncthreads();
  u64* M = mask + (size_t)b * NC * 64;
  for (int chunk = 0; chunk < 16; ++chunk) {
    int j = chunk * 256 + tid;
    float4 cb = boffA[(size_t)b * NCPAD + j];
    float ca = area[(size_t)b * NCPAD + j];
    int wword = chunk * 4 + wave;
#pragma unroll
    for (int rr = 0; rr < RPB; ++rr) {
      int i = row0 + rr;
      float4 rbb = rb[rr];
      float ria = ra[rr];
      float ix1 = fmaxf(cb.x, rbb.x);
      float iy1 = fmaxf(cb.y, rbb.y);
      float ix2 = fminf(cb.z, rbb.z);
      float iy2 = fminf(cb.w, rbb.w);
      float inter = __fmul_rn(fmaxf(__fsub_rn(ix2, ix1), 0.0f),
                              fmaxf(__fsub_rn(iy2, iy1), 0.0f));
      float uni = __fsub_rn(__fadd_rn(ca, ria), inter);
      float iou = __fdiv_rn(inter, (uni > 0.0f) ? uni : 1.0f);
      bool pred = (j > i) && (iou > 0.7f);
      u64 bal = __ballot(pred ? 1 : 0);
      if (lane == 0 && i < NC) M[(size_t)i * 64 + wword] = bal;
    }
  }
}

// ---------------- K5: sequential greedy NMS (chunked, in-register) + compact --
__global__ __launch_bounds__(64) void k_nms(
    const u64* __restrict__ mask, const u64* __restrict__ validmask,
    const float4* __restrict__ sbox, const float* __restrict__ score,
    float* __restrict__ out) {
  int b = blockIdx.x;
  int lane = threadIdx.x;
  const u64* M = mask + (size_t)b * NC * 64;
  __shared__ u64 dch[64];
  u64 supp = 0ull, keep = 0ull;
  u64 valid = validmask[b * 64 + lane];
  for (int c0 = 0; c0 < NC; c0 += 64) {
    int W = c0 >> 6;
    u64 s = __shfl(supp, W);
    u64 v = __shfl(valid, W);
    int row = c0 + lane;
    dch[lane] = (row < NC) ? M[(size_t)row * 64 + W] : 0ull;
    __syncthreads();
    u64 kw = 0ull;
    for (int q = 0; q < 64; ++q) {
      if (((v >> q) & 1ull) && !((s >> q) & 1ull)) {
        s |= dch[q];
        kw |= (1ull << q);
      }
    }
    __syncthreads();
    for (int q = 0; q < 64; ++q) {
      if ((kw >> q) & 1ull) {
        supp |= M[(size_t)(c0 + q) * 64 + lane];
      }
    }
    if (lane == W) keep = kw;
  }
  // rank = exclusive prefix of popcounts across lanes
  int pc = __popcll(keep);
  int incl = pc;
  for (int d = 1; d < 64; d <<= 1) {
    int t = __shfl_up(incl, d);
    if (lane >= d) incl += t;
  }
  int r = incl - pc;
  u64 kk = keep;
  while (kk) {
    int bit = __builtin_ctzll(kk);
    kk &= kk - 1ull;
    if (r < POSTN) {
      int p = lane * 64 + bit;
      float4 bx = sbox[(size_t)b * NCPAD + p];
      size_t ob = ((size_t)b * POSTN + (size_t)r) * 4;
      out[ob + 0] = bx.x;
      out[ob + 1] = bx.y;
      out[ob + 2] = bx.z;
      out[ob + 3] = bx.w;
      out[(size_t)NB * POSTN * 4 + (size_t)b * POSTN + (size_t)r] =
          score[(size_t)b * NCPAD + p];
    }
    ++r;
  }
}

extern "C" void kernel_launch(void* const* d_in, const int* in_sizes, int n_in,
                              void* d_out, int out_size, void* d_ws, size_t ws_size,
                              hipStream_t stream) {
  // setup_inputs dict order: cls0, reg0, cls1, reg1, cls2, reg2, cls3, reg3, anchors
  const float* cls0 = (const float*)d_in[0];
  const float* reg0 = (const float*)d_in[1];
  const float* cls1 = (const float*)d_in[2];
  const float* reg1 = (const float*)d_in[3];
  const float* cls2 = (const float*)d_in[4];
  const float* reg2 = (const float*)d_in[5];
  const float* cls3 = (const float*)d_in[6];
  const float* reg3 = (const float*)d_in[7];
  const float* anchors = (const float*)d_in[8];
  float* out = (float*)d_out;

  char* ws = (char*)d_ws;
  size_t off = 0;
  auto take = [&](size_t bytes) -> void* {
    off = (off + 255) & ~(size_t)255;
    void* p = ws + off;
    off += bytes;
    return p;
  };
  u64* mask      = (u64*)take((size_t)NB * NC * 64 * 8);   // 32.8 MB
  u64* cand_key  = (u64*)take((size_t)NB * NCPAD * 8);
  float4* sbox   = (float4*)take((size_t)NB * NCPAD * 16);
  float4* boffA  = (float4*)take((size_t)NB * NCPAD * 16);
  float* area    = (float*)take((size_t)NB * NCPAD * 4);
  float* score   = (float*)take((size_t)NB * NCPAD * 4);
  u64* validmask = (u64*)take((size_t)NB * 64 * 8);
  u64* kth       = (u64*)take((size_t)NB * 4 * 8);
  u32* counters  = (u32*)take((size_t)NB * 4 * 4);
  (void)ws_size; (void)in_sizes; (void)n_in; (void)out_size;

  k_zero<<<313, 256, 0, stream>>>(out, counters, cand_key);
  k_select<<<64, 1024, 0, stream>>>(cls0, cls1, cls2, cls3, kth);
  k_gather<<<(2550000 + 255) / 256, 256, 0, stream>>>(
      cls0, cls1, cls2, cls3, reg0, reg1, reg2, reg3, anchors, kth, counters,
      cand_key);
  k_sort_decode<<<NB, 1024, 0, stream>>>(cand_key, reg0, reg1, reg2, reg3,
                                         anchors, sbox, boffA, area, score,
                                         validmask);
  k_mask<<<NB * 250, 256, 0, stream>>>(boffA, area, mask);
  k_nms<<<NB, 64, 0, stream>>>(mask, validmask, sbox, score, out);
}

// Round 3
// 1368.745 us; speedup vs baseline: 1.5304x; 1.5304x over previous
//
#include <hip/hip_runtime.h>
#include <cstdint>
#include <cstddef>

typedef uint32_t u32;
typedef uint64_t u64;

#define NB 16
#define NC 4000
#define NCPAD 4096
#define POSTN 1000
#define PREN 1000
#define NCHUNK 63   // ceil(NC/64)

__constant__ int c_N[4]    = {120000, 30000, 7500, 1875};
__constant__ int c_OFF[4]  = {0, 120000, 150000, 157500};
__constant__ int c_HW[4]   = {40000, 10000, 2500, 625};
__constant__ int c_W[4]    = {200, 100, 50, 25};
__constant__ int c_BASE[4] = {0, 1000, 2000, 3000};

__device__ __forceinline__ u32 ord_bits(float f) {
  u32 u = __float_as_uint(f);
  return (u & 0x80000000u) ? ~u : (u | 0x80000000u);
}
__device__ __forceinline__ float inv_ord(u32 o) {
  u32 bits = (o & 0x80000000u) ? (o ^ 0x80000000u) : ~o;
  return __uint_as_float(bits);
}
__device__ __forceinline__ u64 make_key(float f, u32 gid) {
  return ((u64)ord_bits(f) << 32) | (u64)(u32)(~gid);
}

struct DecBox { float x1, y1, x2, y2; int lvl; bool valid; };

__device__ DecBox decode_box(u32 gid, int b,
    const float* __restrict__ reg0, const float* __restrict__ reg1,
    const float* __restrict__ reg2, const float* __restrict__ reg3,
    const float* __restrict__ anchors) {
  int lvl = (gid < 120000u) ? 0 : (gid < 150000u) ? 1 : (gid < 157500u) ? 2 : 3;
  int local = (int)gid - c_OFF[lvl];
  int a = local % 3;
  int cell = local / 3;
  int w = c_W[lvl];
  int hw = c_HW[lvl];
  int y = cell / w;
  int x = cell - y * w;
  const float* reg = (lvl == 0) ? reg0 : (lvl == 1) ? reg1 : (lvl == 2) ? reg2 : reg3;
  size_t base = ((size_t)(b * 12 + a * 4) * (size_t)w + (size_t)y) * (size_t)w + (size_t)x;
  const float CLIPV = 4.135166556742356f; // log(1000/16) as f32
  float dx = reg[base];
  float dy = reg[base + (size_t)hw];
  float dwv = fminf(reg[base + 2 * (size_t)hw], CLIPV);
  float dhv = fminf(reg[base + 3 * (size_t)hw], CLIPV);
  float a0 = anchors[(size_t)gid * 4 + 0];
  float a1 = anchors[(size_t)gid * 4 + 1];
  float a2 = anchors[(size_t)gid * 4 + 2];
  float a3 = anchors[(size_t)gid * 4 + 3];
  float wa = __fsub_rn(a2, a0);
  float ha = __fsub_rn(a3, a1);
  float cxa = __fadd_rn(a0, __fmul_rn(0.5f, wa));
  float cya = __fadd_rn(a1, __fmul_rn(0.5f, ha));
  float pcx = __fadd_rn(__fmul_rn(dx, wa), cxa);
  float pcy = __fadd_rn(__fmul_rn(dy, ha), cya);
  float pw = __fmul_rn(expf(dwv), wa);
  float ph = __fmul_rn(expf(dhv), ha);
  float x1 = __fsub_rn(pcx, __fmul_rn(0.5f, pw));
  float y1 = __fsub_rn(pcy, __fmul_rn(0.5f, ph));
  float x2 = __fadd_rn(pcx, __fmul_rn(0.5f, pw));
  float y2 = __fadd_rn(pcy, __fmul_rn(0.5f, ph));
  x1 = fminf(fmaxf(x1, 0.0f), 800.0f);
  y1 = fminf(fmaxf(y1, 0.0f), 800.0f);
  x2 = fminf(fmaxf(x2, 0.0f), 800.0f);
  y2 = fminf(fmaxf(y2, 0.0f), 800.0f);
  DecBox r;
  r.x1 = x1; r.y1 = y1; r.x2 = x2; r.y2 = y2; r.lvl = lvl;
  r.valid = (__fsub_rn(x2, x1) >= 1.0f) && (__fsub_rn(y2, y1) >= 1.0f);
  return r;
}

// ---------------- K0: zero outputs / counters / candidate keys ----------------
__global__ void k_zero(float* __restrict__ out, u32* __restrict__ counters,
                       u64* __restrict__ cand_key) {
  int i = blockIdx.x * blockDim.x + threadIdx.x;
  if (i < NB * POSTN * 5) out[i] = 0.0f;          // 80000 floats
  if (i < NB * 4) counters[i] = 0u;
  if (i < NB * NCPAD) cand_key[i] = 0ull;
}

// ---------------- K1: exact per-(image,level) radix-select of k-th key --------
__global__ __launch_bounds__(1024) void k_select(
    const float* __restrict__ cls0, const float* __restrict__ cls1,
    const float* __restrict__ cls2, const float* __restrict__ cls3,
    u64* __restrict__ kth) {
  int task = blockIdx.x;         // 0..63
  int b = task & 15;
  int lvl = task >> 4;           // 0..3
  const float* cls = (lvl == 0) ? cls0 : (lvl == 1) ? cls1 : (lvl == 2) ? cls2 : cls3;
  int n = c_N[lvl], hw = c_HW[lvl], off = c_OFF[lvl];
  const float* cp = cls + (size_t)b * (size_t)n;
  __shared__ u32 hist[256];
  __shared__ u64 sh_pval;
  __shared__ u32 sh_kneed;
  int tid = threadIdx.x;
  int lane = tid & 63;
  if (tid == 0) { sh_pval = 0ull; sh_kneed = PREN; }
  u64 pmask = 0ull;
  __syncthreads();
  for (int pass = 7; pass >= 0; --pass) {
    int shift = pass * 8;
    __syncthreads();
    if (tid < 256) hist[tid] = 0u;
    __syncthreads();
    u64 pval = sh_pval;
    for (int e = tid; e < n; e += 1024) {
      float f = cp[e];
      int a = e / hw;
      int cell = e - a * hw;
      u32 gid = (u32)(off + cell * 3 + a);
      u64 key = make_key(f, gid);
      bool cnt = ((key & pmask) == pval);
      u32 bucket = (u32)(key >> shift) & 255u;
      // wave-aggregated histogram: one atomic per unique bucket per wave
      u64 active = __ballot(cnt ? 1 : 0);
      while (active) {
        int leader = __builtin_ctzll(active);
        u32 lb = __shfl(bucket, leader);
        u64 eq = __ballot((cnt && bucket == lb) ? 1 : 0);
        if (lane == leader) atomicAdd(&hist[lb], (u32)__popcll(eq));
        active &= ~eq;
      }
    }
    __syncthreads();
    if (tid == 0) {
      u32 kneed = sh_kneed;
      u32 acc = 0;
      for (int bq = 255; bq >= 0; --bq) {
        u32 c = hist[bq];
        if (acc + c >= kneed) {
          sh_pval = pval | ((u64)(u32)bq << shift);
          sh_kneed = kneed - acc;
          break;
        }
        acc += c;
      }
    }
    pmask |= (0xFFull << shift);
    __syncthreads();
  }
  if (tid == 0) kth[b * 4 + lvl] = sh_pval;
}

// ---------------- K2: gather selected candidates, build sort keys -------------
__global__ void k_gather(
    const float* __restrict__ cls0, const float* __restrict__ cls1,
    const float* __restrict__ cls2, const float* __restrict__ cls3,
    const float* __restrict__ reg0, const float* __restrict__ reg1,
    const float* __restrict__ reg2, const float* __restrict__ reg3,
    const float* __restrict__ anchors, const u64* __restrict__ kth,
    u32* __restrict__ counters, u64* __restrict__ cand_key) {
  int e = blockIdx.x * blockDim.x + threadIdx.x;
  const int S1 = 1920000, S2 = 2400000, S3 = 2520000, S4 = 2550000;
  if (e >= S4) return;
  int l, r;
  if (e < S1)      { l = 0; r = e; }
  else if (e < S2) { l = 1; r = e - S1; }
  else if (e < S3) { l = 2; r = e - S2; }
  else             { l = 3; r = e - S3; }
  int n = c_N[l], hw = c_HW[l];
  int b = r / n;
  int m = r - b * n;        // memory order within (a, y, x)
  int a = m / hw;
  int cell = m - a * hw;
  u32 gid = (u32)(c_OFF[l] + cell * 3 + a);
  const float* cls = (l == 0) ? cls0 : (l == 1) ? cls1 : (l == 2) ? cls2 : cls3;
  float f = cls[(size_t)b * (size_t)n + (size_t)m];
  u64 key = make_key(f, gid);
  bool sel = (key >= kth[b * 4 + l]);
  if (sel) {
    DecBox bx = decode_box(gid, b, reg0, reg1, reg2, reg3, anchors);
    u64 skey = bx.valid ? key : (key & 0xFFFFFFFFull); // invalid sorts after all valid
    u32 slot = atomicAdd(&counters[b * 4 + l], 1u);
    if (slot < (u32)PREN)
      cand_key[(size_t)b * NCPAD + (size_t)(c_BASE[l] + (int)slot)] = skey;
  }
}

// ---------------- K3: per-image bitonic sort (desc) + decode payloads ---------
__global__ __launch_bounds__(1024) void k_sort_decode(
    const u64* __restrict__ cand_key,
    const float* __restrict__ reg0, const float* __restrict__ reg1,
    const float* __restrict__ reg2, const float* __restrict__ reg3,
    const float* __restrict__ anchors,
    float4* __restrict__ sbox, float4* __restrict__ boffA,
    float* __restrict__ area, float* __restrict__ score,
    u64* __restrict__ validmask) {
  int b = blockIdx.x;
  int tid = threadIdx.x;
  __shared__ u64 sk[NCPAD];
  for (int p = tid; p < NCPAD; p += 1024) sk[p] = cand_key[(size_t)b * NCPAD + p];
  __syncthreads();
  for (u32 k = 2; k <= NCPAD; k <<= 1) {
    for (u32 j = k >> 1; j > 0; j >>= 1) {
      for (u32 t = tid; t < NCPAD / 2; t += 1024) {
        u32 i = 2u * t - (t & (j - 1u));
        u32 l2 = i | j;
        u64 av = sk[i], bv = sk[l2];
        bool up = ((i & k) == 0u);
        if (up ? (av < bv) : (av > bv)) { sk[i] = bv; sk[l2] = av; }
      }
      __syncthreads();
    }
  }
  for (int c = 0; c < 4; ++c) {
    int p = c * 1024 + tid;
    u64 key = sk[p];
    float4 bx4 = make_float4(0.f, 0.f, 0.f, 0.f);
    float4 bo4 = make_float4(0.f, 0.f, 0.f, 0.f);
    float ar = 0.f, sc = 0.f;
    bool vflag = false;
    if (key != 0ull) {
      u32 gid = ~((u32)key);
      vflag = (key >> 32) != 0ull;
      DecBox bx = decode_box(gid, b, reg0, reg1, reg2, reg3, anchors);
      bx4 = make_float4(bx.x1, bx.y1, bx.x2, bx.y2);
      float offv = __fmul_rn((float)bx.lvl, 801.0f);
      bo4 = make_float4(__fadd_rn(bx.x1, offv), __fadd_rn(bx.y1, offv),
                        __fadd_rn(bx.x2, offv), __fadd_rn(bx.y2, offv));
      ar = __fmul_rn(__fsub_rn(bo4.z, bo4.x), __fsub_rn(bo4.w, bo4.y));
      if (vflag) {
        float logit = inv_ord((u32)(key >> 32));
        sc = 1.0f / (1.0f + expf(-logit));
      }
    }
    size_t gi = (size_t)b * NCPAD + (size_t)p;
    sbox[gi] = bx4;
    boffA[gi] = bo4;
    area[gi] = ar;
    score[gi] = sc;
    u64 bal = __ballot(vflag ? 1 : 0);
    if ((tid & 63) == 0) validmask[b * 64 + (p >> 6)] = bal;
  }
}

// ---------------- K4: IoU suppression bitmask matrix --------------------------
#define RPB 16
__global__ __launch_bounds__(256) void k_mask(
    const float4* __restrict__ boffA, const float* __restrict__ area,
    u64* __restrict__ mask) {
  int bg = blockIdx.x;
  int b = bg / 250;
  int g = bg - b * 250;
  int row0 = g * RPB;
  int tid = threadIdx.x;
  int wave = tid >> 6;
  int lane = tid & 63;
  __shared__ float4 rb[RPB];
  __shared__ float ra[RPB];
  if (tid < RPB) {
    int rr = row0 + tid;
    int rc = (rr < NCPAD) ? rr : (NCPAD - 1);
    rb[tid] = boffA[(size_t)b * NCPAD + rc];
    ra[tid] = area[(size_t)b * NCPAD + rc];
  }
  __syncthreads();
  u64* M = mask + (size_t)b * NC * 64;
  for (int chunk = 0; chunk < 16; ++chunk) {
    int j = chunk * 256 + tid;
    float4 cb = boffA[(size_t)b * NCPAD + j];
    float ca = area[(size_t)b * NCPAD + j];
    int wword = chunk * 4 + wave;
#pragma unroll
    for (int rr = 0; rr < RPB; ++rr) {
      int i = row0 + rr;
      float4 rbb = rb[rr];
      float ria = ra[rr];
      float ix1 = fmaxf(cb.x, rbb.x);
      float iy1 = fmaxf(cb.y, rbb.y);
      float ix2 = fminf(cb.z, rbb.z);
      float iy2 = fminf(cb.w, rbb.w);
      float inter = __fmul_rn(fmaxf(__fsub_rn(ix2, ix1), 0.0f),
                              fmaxf(__fsub_rn(iy2, iy1), 0.0f));
      float uni = __fsub_rn(__fadd_rn(ca, ria), inter);
      float iou = __fdiv_rn(inter, (uni > 0.0f) ? uni : 1.0f);
      bool pred = (j > i) && (iou > 0.7f);
      u64 bal = __ballot(pred ? 1 : 0);
      if (lane == 0 && i < NC) M[(size_t)i * 64 + wword] = bal;
    }
  }
}

// ---------------- K5: greedy NMS — parallel resolve/OR (1024 thr/image) -------
__global__ __launch_bounds__(1024) void k_nms(
    const u64* __restrict__ mask, const u64* __restrict__ validmask,
    const float4* __restrict__ sbox, const float* __restrict__ score,
    float* __restrict__ out) {
  int b = blockIdx.x;
  int tid = threadIdx.x;
  int wid = tid >> 6;
  int lane = tid & 63;
  const u64* M = mask + (size_t)b * NC * 64;
  __shared__ u64 supp_lds[64];
  __shared__ u64 dch_lds[2][64];
  __shared__ u64 kw_lds;
  __shared__ u64 keepw[64];
  if (tid < 64) { supp_lds[tid] = 0ull; keepw[tid] = 0ull; }
  if (wid == 0) {
    // prologue: chunk 0 diagonal block (rows 0..63 all < NC)
    dch_lds[0][lane] = M[(size_t)lane * 64 + 0];
  }
  __syncthreads();
  for (int W = 0; W < NCHUNK; ++W) {
    int c0 = W << 6;
    if (wid == 0) {
      // serial greedy resolve, in-register (iterations = #kept in chunk)
      u64 dch = dch_lds[W & 1][lane];
      u64 s = supp_lds[W];
      u64 v = validmask[b * 64 + W];
      u64 pending = v & ~s;
      u64 kw = 0ull;
      while (pending) {
        int q = __builtin_ctzll(pending);
        kw |= (1ull << q);
        u64 supq = __shfl(dch, q);   // row q only sets bits > q
        pending &= ~supq;
        pending &= ~(1ull << q);
      }
      if (lane == 0) { kw_lds = kw; keepw[W] = kw; }
    } else if (wid == 1 && W + 1 < NCHUNK) {
      // prefetch next chunk's diagonal block
      int row = (W + 1) * 64 + lane;
      dch_lds[(W + 1) & 1][lane] =
          (row < NC) ? M[(size_t)row * 64 + (W + 1)] : 0ull;
    }
    __syncthreads();
    u64 kw = kw_lds;
    // parallel OR of kept rows into the global suppression bitset
    u64 acc = 0ull;
#pragma unroll
    for (int t = 0; t < 4; ++t) {
      int q = wid + (t << 4);
      if ((kw >> q) & 1ull) acc |= M[(size_t)(c0 + q) * 64 + lane];
    }
    if (acc) atomicOr((unsigned long long*)&supp_lds[lane],
                      (unsigned long long)acc);
    __syncthreads();
  }
  if (wid == 0) {
    u64 keep = (lane < NCHUNK) ? keepw[lane] : 0ull;
    int pc = __popcll(keep);
    int incl = pc;
    for (int d = 1; d < 64; d <<= 1) {
      int t = __shfl_up(incl, d);
      if (lane >= d) incl += t;
    }
    int r = incl - pc;
    u64 kk = keep;
    while (kk) {
      int bit = __builtin_ctzll(kk);
      kk &= kk - 1ull;
      if (r < POSTN) {
        int p = lane * 64 + bit;
        float4 bx = sbox[(size_t)b * NCPAD + p];
        size_t ob = ((size_t)b * POSTN + (size_t)r) * 4;
        out[ob + 0] = bx.x;
        out[ob + 1] = bx.y;
        out[ob + 2] = bx.z;
        out[ob + 3] = bx.w;
        out[(size_t)NB * POSTN * 4 + (size_t)b * POSTN + (size_t)r] =
            score[(size_t)b * NCPAD + p];
      }
      ++r;
    }
  }
}

extern "C" void kernel_launch(void* const* d_in, const int* in_sizes, int n_in,
                              void* d_out, int out_size, void* d_ws, size_t ws_size,
                              hipStream_t stream) {
  // setup_inputs dict order: cls0, reg0, cls1, reg1, cls2, reg2, cls3, reg3, anchors
  const float* cls0 = (const float*)d_in[0];
  const float* reg0 = (const float*)d_in[1];
  const float* cls1 = (const float*)d_in[2];
  const float* reg1 = (const float*)d_in[3];
  const float* cls2 = (const float*)d_in[4];
  const float* reg2 = (const float*)d_in[5];
  const float* cls3 = (const float*)d_in[6];
  const float* reg3 = (const float*)d_in[7];
  const float* anchors = (const float*)d_in[8];
  float* out = (float*)d_out;

  char* ws = (char*)d_ws;
  size_t off = 0;
  auto take = [&](size_t bytes) -> void* {
    off = (off + 255) & ~(size_t)255;
    void* p = ws + off;
    off += bytes;
    return p;
  };
  u64* mask      = (u64*)take((size_t)NB * NC * 64 * 8);   // 32.8 MB
  u64* cand_key  = (u64*)take((size_t)NB * NCPAD * 8);
  float4* sbox   = (float4*)take((size_t)NB * NCPAD * 16);
  float4* boffA  = (float4*)take((size_t)NB * NCPAD * 16);
  float* area    = (float*)take((size_t)NB * NCPAD * 4);
  float* score   = (float*)take((size_t)NB * NCPAD * 4);
  u64* validmask = (u64*)take((size_t)NB * 64 * 8);
  u64* kth       = (u64*)take((size_t)NB * 4 * 8);
  u32* counters  = (u32*)take((size_t)NB * 4 * 4);
  (void)ws_size; (void)in_sizes; (void)n_in; (void)out_size;

  k_zero<<<313, 256, 0, stream>>>(out, counters, cand_key);
  k_select<<<64, 1024, 0, stream>>>(cls0, cls1, cls2, cls3, kth);
  k_gather<<<(2550000 + 255) / 256, 256, 0, stream>>>(
      cls0, cls1, cls2, cls3, reg0, reg1, reg2, reg3, anchors, kth, counters,
      cand_key);
  k_sort_decode<<<NB, 1024, 0, stream>>>(cand_key, reg0, reg1, reg2, reg3,
                                         anchors, sbox, boffA, area, score,
                                         validmask);
  k_mask<<<NB * 250, 256, 0, stream>>>(boffA, area, mask);
  k_nms<<<NB, 1024, 0, stream>>>(mask, validmask, sbox, score, out);
}

// Round 4
// 796.926 us; speedup vs baseline: 2.6285x; 1.7175x over previous
//
#include <hip/hip_runtime.h>
#include <cstdint>
#include <cstddef>

typedef uint32_t u32;
typedef uint64_t u64;

#define NB 16
#define NC 4000
#define NCPAD 4096
#define POSTN 1000
#define PREN 1000
#define NCHUNK 63   // ceil(NC/64)
#define TIECAP 8192

__constant__ int c_N[4]    = {120000, 30000, 7500, 1875};
__constant__ int c_OFF[4]  = {0, 120000, 150000, 157500};
__constant__ int c_HW[4]   = {40000, 10000, 2500, 625};
__constant__ int c_W[4]    = {200, 100, 50, 25};
__constant__ int c_BASE[4] = {0, 1000, 2000, 3000};
__constant__ int c_KOFF[4] = {0, 1920000, 2400000, 2520000};

__device__ __forceinline__ u32 ord_bits(float f) {
  u32 u = __float_as_uint(f);
  return (u & 0x80000000u) ? ~u : (u | 0x80000000u);
}
__device__ __forceinline__ float inv_ord(u32 o) {
  u32 bits = (o & 0x80000000u) ? (o ^ 0x80000000u) : ~o;
  return __uint_as_float(bits);
}

// 192-block slice map: 8 blocks/task lvl0, 2/task lvl1, 1/task lvl2+3
__device__ __forceinline__ void slice_map(int bid, int& lvl, int& b, int& e0,
                                          int& nsl) {
  if (bid < 128)      { lvl = 0; b = bid >> 3; e0 = (bid & 7) * 15000; nsl = 15000; }
  else if (bid < 160) { lvl = 1; int t = bid - 128; b = t >> 1; e0 = (t & 1) * 15000; nsl = 15000; }
  else if (bid < 176) { lvl = 2; b = bid - 160; e0 = 0; nsl = 7500; }
  else                { lvl = 3; b = bid - 176; e0 = 0; nsl = 1875; }
}

struct DecBox { float x1, y1, x2, y2; int lvl; bool valid; };

__device__ DecBox decode_box(u32 gid, int b,
    const float* __restrict__ reg0, const float* __restrict__ reg1,
    const float* __restrict__ reg2, const float* __restrict__ reg3,
    const float* __restrict__ anchors) {
  int lvl = (gid < 120000u) ? 0 : (gid < 150000u) ? 1 : (gid < 157500u) ? 2 : 3;
  int local = (int)gid - c_OFF[lvl];
  int a = local % 3;
  int cell = local / 3;
  int w = c_W[lvl];
  int hw = c_HW[lvl];
  int y = cell / w;
  int x = cell - y * w;
  const float* reg = (lvl == 0) ? reg0 : (lvl == 1) ? reg1 : (lvl == 2) ? reg2 : reg3;
  size_t base = ((size_t)(b * 12 + a * 4) * (size_t)w + (size_t)y) * (size_t)w + (size_t)x;
  const float CLIPV = 4.135166556742356f; // log(1000/16) as f32
  float dx = reg[base];
  float dy = reg[base + (size_t)hw];
  float dwv = fminf(reg[base + 2 * (size_t)hw], CLIPV);
  float dhv = fminf(reg[base + 3 * (size_t)hw], CLIPV);
  float a0 = anchors[(size_t)gid * 4 + 0];
  float a1 = anchors[(size_t)gid * 4 + 1];
  float a2 = anchors[(size_t)gid * 4 + 2];
  float a3 = anchors[(size_t)gid * 4 + 3];
  float wa = __fsub_rn(a2, a0);
  float ha = __fsub_rn(a3, a1);
  float cxa = __fadd_rn(a0, __fmul_rn(0.5f, wa));
  float cya = __fadd_rn(a1, __fmul_rn(0.5f, ha));
  float pcx = __fadd_rn(__fmul_rn(dx, wa), cxa);
  float pcy = __fadd_rn(__fmul_rn(dy, ha), cya);
  float pw = __fmul_rn(expf(dwv), wa);
  float ph = __fmul_rn(expf(dhv), ha);
  float x1 = __fsub_rn(pcx, __fmul_rn(0.5f, pw));
  float y1 = __fsub_rn(pcy, __fmul_rn(0.5f, ph));
  float x2 = __fadd_rn(pcx, __fmul_rn(0.5f, pw));
  float y2 = __fadd_rn(pcy, __fmul_rn(0.5f, ph));
  x1 = fminf(fmaxf(x1, 0.0f), 800.0f);
  y1 = fminf(fmaxf(y1, 0.0f), 800.0f);
  x2 = fminf(fmaxf(x2, 0.0f), 800.0f);
  y2 = fminf(fmaxf(y2, 0.0f), 800.0f);
  DecBox r;
  r.x1 = x1; r.y1 = y1; r.x2 = x2; r.y2 = y2; r.lvl = lvl;
  r.valid = (__fsub_rn(x2, x1) >= 1.0f) && (__fsub_rn(y2, y1) >= 1.0f);
  return r;
}

// ---------------- K0: zero state ----------------------------------------------
__global__ void k_zero(float* __restrict__ out, u32* __restrict__ counters,
                       u64* __restrict__ cand_key, u32* __restrict__ hist1,
                       u32* __restrict__ hist2, u32* __restrict__ hist3,
                       u32* __restrict__ tiecnt, u32* __restrict__ resolvedf,
                       u32* __restrict__ state_known,
                       u32* __restrict__ state_kneed) {
  int i = blockIdx.x * blockDim.x + threadIdx.x;
  if (i < NB * POSTN * 5) out[i] = 0.0f;
  if (i < NB * NCPAD) cand_key[i] = 0ull;
  if (i < 64 * 2048) { hist1[i] = 0u; hist2[i] = 0u; hist3[i] = 0u; }
  if (i < 64) {
    counters[i] = 0u; tiecnt[i] = 0u; resolvedf[i] = 0u;
    state_known[i] = 0u; state_kneed[i] = (u32)PREN;
  }
}

// ---------------- K1: ord keys + pass-1 histogram (full chip) -----------------
__global__ __launch_bounds__(1024) void k_keys(
    const float* __restrict__ cls0, const float* __restrict__ cls1,
    const float* __restrict__ cls2, const float* __restrict__ cls3,
    u32* __restrict__ keybuf, u32* __restrict__ hist1) {
  int lvl, b, e0, nsl;
  slice_map(blockIdx.x, lvl, b, e0, nsl);
  const float* cls = (lvl == 0) ? cls0 : (lvl == 1) ? cls1 : (lvl == 2) ? cls2 : cls3;
  int n = c_N[lvl];
  const float* cp = cls + (size_t)b * n;
  u32* kb = keybuf + c_KOFF[lvl] + b * n;
  int tid = threadIdx.x;
  __shared__ u32 h[2048];
  for (int t = tid; t < 2048; t += 1024) h[t] = 0u;
  __syncthreads();
  for (int e = e0 + tid; e < e0 + nsl; e += 1024) {
    u32 o = ord_bits(cp[e]);
    kb[e] = o;
    atomicAdd(&h[o >> 21], 1u);
  }
  __syncthreads();
  int task = lvl * 16 + b;
  for (int t = tid; t < 2048; t += 1024) {
    u32 v = h[t];
    if (v) atomicAdd(&hist1[task * 2048 + t], v);
  }
}

// ---------------- K2/K3: filtered histogram passes -----------------------------
__global__ __launch_bounds__(1024) void k_hist(
    const u32* __restrict__ keybuf, const u32* __restrict__ state_known,
    u32* __restrict__ hist, int shift, u32 fmask, u32 dmask) {
  int lvl, b, e0, nsl;
  slice_map(blockIdx.x, lvl, b, e0, nsl);
  int task = lvl * 16 + b;
  u32 known = state_known[task];
  const u32* kb = keybuf + c_KOFF[lvl] + b * c_N[lvl];
  int tid = threadIdx.x;
  __shared__ u32 h[2048];
  for (int t = tid; t <= (int)dmask; t += 1024) h[t] = 0u;
  __syncthreads();
  for (int e = e0 + tid; e < e0 + nsl; e += 1024) {
    u32 o = kb[e];
    if ((o & fmask) == known) atomicAdd(&h[(o >> shift) & dmask], 1u);
  }
  __syncthreads();
  for (int t = tid; t <= (int)dmask; t += 1024) {
    u32 v = h[t];
    if (v) atomicAdd(&hist[task * 2048 + t], v);
  }
}

// ---------------- K pick: suffix-scan histogram, choose digit ------------------
__global__ __launch_bounds__(1024) void k_pick(
    const u32* __restrict__ hist, u32* __restrict__ state_known,
    u32* __restrict__ state_kneed, u32* __restrict__ resolvedf,
    u64* __restrict__ kth, int nb, int shift, int final_pass) {
  int task = blockIdx.x;
  int tid = threadIdx.x;
  __shared__ u32 A[2048], Bb[2048];
  __shared__ int sh_t;
  __shared__ u32 sh_above;
  u32 kneed = state_kneed[task];
  for (int t = tid; t < nb; t += 1024) A[t] = hist[task * 2048 + t];
  __syncthreads();
  u32* cur = A;
  u32* nxt = Bb;
  for (int off2 = 1; off2 < nb; off2 <<= 1) {
    for (int t = tid; t < nb; t += 1024)
      nxt[t] = cur[t] + ((t + off2 < nb) ? cur[t + off2] : 0u);
    __syncthreads();
    u32* tmp = cur; cur = nxt; nxt = tmp;
  }
  // cur[t] = count of elements with digit >= t
  for (int t = tid; t < nb; t += 1024) {
    u32 s = cur[t];
    u32 above = (t + 1 < nb) ? cur[t + 1] : 0u;
    if (s >= kneed && above < kneed) { sh_t = t; sh_above = above; }
  }
  __syncthreads();
  if (tid == 0) {
    u32 known = state_known[task] | ((u32)sh_t << shift);
    u32 kneed2 = kneed - sh_above;
    state_known[task] = known;
    state_kneed[task] = kneed2;
    if (final_pass) {
      u32 c = cur[sh_t] - sh_above;   // count equal to kth value
      if (kneed2 == c) {
        resolvedf[task] = 1u;
        kth[task] = ((u64)known) << 32;   // take all value-equals
      } else {
        resolvedf[task] = 0u;             // gid tie-break needed
      }
    }
  }
}

// ---------------- K tie: collect gids of value-equal elements ------------------
__global__ __launch_bounds__(1024) void k_tie(
    const u32* __restrict__ keybuf, const u32* __restrict__ state_known,
    const u32* __restrict__ resolvedf, u32* __restrict__ tiecnt,
    u32* __restrict__ tiebuf) {
  int lvl, b, e0, nsl;
  slice_map(blockIdx.x, lvl, b, e0, nsl);
  int task = lvl * 16 + b;
  if (resolvedf[task]) return;
  u32 pval = state_known[task];
  const u32* kb = keybuf + c_KOFF[lvl] + b * c_N[lvl];
  int hw = c_HW[lvl], off = c_OFF[lvl];
  for (int e = e0 + threadIdx.x; e < e0 + nsl; e += 1024) {
    if (kb[e] == pval) {
      int a = e / hw;
      int cell = e - a * hw;
      u32 gid = (u32)(off + cell * 3 + a);
      u32 idx = atomicAdd(&tiecnt[task], 1u);
      if (idx < (u32)TIECAP) tiebuf[task * TIECAP + idx] = gid;
    }
  }
}

// ---------------- K tiepick: kneed-th smallest gid among equals ----------------
__global__ __launch_bounds__(1024) void k_tiepick(
    const u32* __restrict__ tiecnt, const u32* __restrict__ tiebuf,
    const u32* __restrict__ state_known, const u32* __restrict__ state_kneed,
    const u32* __restrict__ resolvedf, u64* __restrict__ kth) {
  int task = blockIdx.x;
  if (resolvedf[task]) return;
  int tid = threadIdx.x;
  __shared__ u32 G[TIECAP];
  __shared__ u32 h[256];
  __shared__ u32 sh_known, sh_kneed;
  u32 c2 = min(tiecnt[task], (u32)TIECAP);
  for (u32 i = tid; i < c2; i += 1024) G[i] = tiebuf[task * TIECAP + i];
  if (tid == 0) { sh_known = 0u; sh_kneed = state_kneed[task]; }
  u32 pmask = 0u;
  __syncthreads();
  for (int pass = 2; pass >= 0; --pass) {  // gid < 2^18 < 2^24
    int shift = pass * 8;
    if (tid < 256) h[tid] = 0u;
    __syncthreads();
    u32 known = sh_known;
    for (u32 i = tid; i < c2; i += 1024) {
      u32 g = G[i];
      if ((g & pmask) == known) atomicAdd(&h[(g >> shift) & 255u], 1u);
    }
    __syncthreads();
    if (tid == 0) {
      u32 kneed = sh_kneed;
      u32 cum = 0;
      for (int t = 0; t < 256; ++t) {   // ascending: kneed-th SMALLEST gid
        u32 v = h[t];
        if (cum + v >= kneed) {
          sh_known = known | ((u32)t << shift);
          sh_kneed = kneed - cum;
          break;
        }
        cum += v;
      }
    }
    pmask |= (0xFFu << shift);
    __syncthreads();
  }
  if (tid == 0)
    kth[task] = (((u64)state_known[task]) << 32) | (u32)(~sh_known);
}

// ---------------- K gather: threshold test + decode + slot write ---------------
__global__ __launch_bounds__(1024) void k_gather(
    const u32* __restrict__ keybuf, const u64* __restrict__ kth,
    const float* __restrict__ reg0, const float* __restrict__ reg1,
    const float* __restrict__ reg2, const float* __restrict__ reg3,
    const float* __restrict__ anchors, u32* __restrict__ counters,
    u64* __restrict__ cand_key) {
  int lvl, b, e0, nsl;
  slice_map(blockIdx.x, lvl, b, e0, nsl);
  int task = lvl * 16 + b;
  u64 kt = kth[task];
  u32 hi = (u32)(kt >> 32);
  const u32* kb = keybuf + c_KOFF[lvl] + b * c_N[lvl];
  int hw = c_HW[lvl], off = c_OFF[lvl];
  for (int e = e0 + threadIdx.x; e < e0 + nsl; e += 1024) {
    u32 o = kb[e];
    if (o < hi) continue;
    int a = e / hw;
    int cell = e - a * hw;
    u32 gid = (u32)(off + cell * 3 + a);
    u64 key = ((u64)o << 32) | (u32)(~gid);
    if (key < kt) continue;
    DecBox bx = decode_box(gid, b, reg0, reg1, reg2, reg3, anchors);
    u64 skey = bx.valid ? key : (key & 0xFFFFFFFFull);
    u32 slot = atomicAdd(&counters[task], 1u);
    if (slot < (u32)PREN)
      cand_key[(size_t)b * NCPAD + (size_t)(c_BASE[lvl] + (int)slot)] = skey;
  }
}

// ---------------- K sort: per-image bitonic sort (desc) of 4096 keys -----------
__global__ __launch_bounds__(1024) void k_sort(u64* __restrict__ cand_key) {
  int b = blockIdx.x;
  int tid = threadIdx.x;
  __shared__ u64 sk[NCPAD];
  for (int p = tid; p < NCPAD; p += 1024) sk[p] = cand_key[(size_t)b * NCPAD + p];
  __syncthreads();
  for (u32 k = 2; k <= NCPAD; k <<= 1) {
    for (u32 j = k >> 1; j > 0; j >>= 1) {
      for (u32 t = tid; t < NCPAD / 2; t += 1024) {
        u32 i = 2u * t - (t & (j - 1u));
        u32 l2 = i | j;
        u64 av = sk[i], bv = sk[l2];
        bool up = ((i & k) == 0u);
        if (up ? (av < bv) : (av > bv)) { sk[i] = bv; sk[l2] = av; }
      }
      __syncthreads();
    }
  }
  for (int p = tid; p < NCPAD; p += 1024) cand_key[(size_t)b * NCPAD + p] = sk[p];
}

// ---------------- K decode: payloads for sorted candidates (full grid) ---------
__global__ __launch_bounds__(1024) void k_decode(
    const u64* __restrict__ cand_key,
    const float* __restrict__ reg0, const float* __restrict__ reg1,
    const float* __restrict__ reg2, const float* __restrict__ reg3,
    const float* __restrict__ anchors,
    float4* __restrict__ sbox, float4* __restrict__ boffA,
    float* __restrict__ area, float* __restrict__ score,
    u64* __restrict__ validmask) {
  int bid = blockIdx.x;
  int b = bid >> 2;
  int p = ((bid & 3) << 10) | threadIdx.x;
  u64 key = cand_key[(size_t)b * NCPAD + p];
  float4 bx4 = make_float4(0.f, 0.f, 0.f, 0.f);
  float4 bo4 = make_float4(0.f, 0.f, 0.f, 0.f);
  float ar = 0.f, sc = 0.f;
  bool vflag = false;
  if (key != 0ull) {
    u32 gid = ~((u32)key);
    vflag = (key >> 32) != 0ull;
    DecBox bx = decode_box(gid, b, reg0, reg1, reg2, reg3, anchors);
    bx4 = make_float4(bx.x1, bx.y1, bx.x2, bx.y2);
    float offv = __fmul_rn((float)bx.lvl, 801.0f);
    bo4 = make_float4(__fadd_rn(bx.x1, offv), __fadd_rn(bx.y1, offv),
                      __fadd_rn(bx.x2, offv), __fadd_rn(bx.y2, offv));
    ar = __fmul_rn(__fsub_rn(bo4.z, bo4.x), __fsub_rn(bo4.w, bo4.y));
    if (vflag) {
      float logit = inv_ord((u32)(key >> 32));
      sc = 1.0f / (1.0f + expf(-logit));
    }
  }
  size_t gi = (size_t)b * NCPAD + (size_t)p;
  sbox[gi] = bx4;
  boffA[gi] = bo4;
  area[gi] = ar;
  score[gi] = sc;
  u64 bal = __ballot(vflag ? 1 : 0);
  if ((threadIdx.x & 63) == 0) validmask[b * 64 + (p >> 6)] = bal;
}

// ---------------- K mask: IoU suppression bitmask matrix -----------------------
#define RPB 16
__global__ __launch_bounds__(256) void k_mask(
    const float4* __restrict__ boffA, const float* __restrict__ area,
    u64* __restrict__ mask) {
  int bg = blockIdx.x;
  int b = bg / 250;
  int g = bg - b * 250;
  int row0 = g * RPB;
  int tid = threadIdx.x;
  int wave = tid >> 6;
  int lane = tid & 63;
  __shared__ float4 rb[RPB];
  __shared__ float ra[RPB];
  if (tid < RPB) {
    int rr = row0 + tid;
    int rc = (rr < NCPAD) ? rr : (NCPAD - 1);
    rb[tid] = boffA[(size_t)b * NCPAD + rc];
    ra[tid] = area[(size_t)b * NCPAD + rc];
  }
  __syncthreads();
  u64* M = mask + (size_t)b * NC * 64;
  for (int chunk = 0; chunk < 16; ++chunk) {
    int j = chunk * 256 + tid;
    float4 cb = boffA[(size_t)b * NCPAD + j];
    float ca = area[(size_t)b * NCPAD + j];
    int wword = chunk * 4 + wave;
#pragma unroll
    for (int rr = 0; rr < RPB; ++rr) {
      int i = row0 + rr;
      float4 rbb = rb[rr];
      float ria = ra[rr];
      float ix1 = fmaxf(cb.x, rbb.x);
      float iy1 = fmaxf(cb.y, rbb.y);
      float ix2 = fminf(cb.z, rbb.z);
      float iy2 = fminf(cb.w, rbb.w);
      float inter = __fmul_rn(fmaxf(__fsub_rn(ix2, ix1), 0.0f),
                              fmaxf(__fsub_rn(iy2, iy1), 0.0f));
      float uni = __fsub_rn(__fadd_rn(ca, ria), inter);
      float iou = __fdiv_rn(inter, (uni > 0.0f) ? uni : 1.0f);
      bool pred = (j > i) && (iou > 0.7f);
      u64 bal = __ballot(pred ? 1 : 0);
      if (lane == 0 && i < NC) M[(size_t)i * 64 + wword] = bal;
    }
  }
}

// ---------------- K nms: greedy NMS, parallel resolve/OR ----------------------
__global__ __launch_bounds__(1024) void k_nms(
    const u64* __restrict__ mask, const u64* __restrict__ validmask,
    const float4* __restrict__ sbox, const float* __restrict__ score,
    float* __restrict__ out) {
  int b = blockIdx.x;
  int tid = threadIdx.x;
  int wid = tid >> 6;
  int lane = tid & 63;
  const u64* M = mask + (size_t)b * NC * 64;
  __shared__ u64 supp_lds[64];
  __shared__ u64 dch_lds[2][64];
  __shared__ u64 kw_lds;
  __shared__ u64 keepw[64];
  if (tid < 64) { supp_lds[tid] = 0ull; keepw[tid] = 0ull; }
  if (wid == 0) {
    dch_lds[0][lane] = M[(size_t)lane * 64 + 0];
  }
  __syncthreads();
  for (int W = 0; W < NCHUNK; ++W) {
    int c0 = W << 6;
    if (wid == 0) {
      u64 dch = dch_lds[W & 1][lane];
      u64 s = supp_lds[W];
      u64 v = validmask[b * 64 + W];
      u64 pending = v & ~s;
      u64 kw = 0ull;
      while (pending) {
        int q = __builtin_ctzll(pending);
        kw |= (1ull << q);
        u64 supq = __shfl(dch, q);
        pending &= ~supq;
        pending &= ~(1ull << q);
      }
      if (lane == 0) { kw_lds = kw; keepw[W] = kw; }
    } else if (wid == 1 && W + 1 < NCHUNK) {
      int row = (W + 1) * 64 + lane;
      dch_lds[(W + 1) & 1][lane] =
          (row < NC) ? M[(size_t)row * 64 + (W + 1)] : 0ull;
    }
    __syncthreads();
    u64 kw = kw_lds;
    u64 acc = 0ull;
#pragma unroll
    for (int t = 0; t < 4; ++t) {
      int q = wid + (t << 4);
      if ((kw >> q) & 1ull) acc |= M[(size_t)(c0 + q) * 64 + lane];
    }
    if (acc) atomicOr((unsigned long long*)&supp_lds[lane],
                      (unsigned long long)acc);
    __syncthreads();
  }
  if (wid == 0) {
    u64 keep = (lane < NCHUNK) ? keepw[lane] : 0ull;
    int pc = __popcll(keep);
    int incl = pc;
    for (int d = 1; d < 64; d <<= 1) {
      int t = __shfl_up(incl, d);
      if (lane >= d) incl += t;
    }
    int r = incl - pc;
    u64 kk = keep;
    while (kk) {
      int bit = __builtin_ctzll(kk);
      kk &= kk - 1ull;
      if (r < POSTN) {
        int p = lane * 64 + bit;
        float4 bx = sbox[(size_t)b * NCPAD + p];
        size_t ob = ((size_t)b * POSTN + (size_t)r) * 4;
        out[ob + 0] = bx.x;
        out[ob + 1] = bx.y;
        out[ob + 2] = bx.z;
        out[ob + 3] = bx.w;
        out[(size_t)NB * POSTN * 4 + (size_t)b * POSTN + (size_t)r] =
            score[(size_t)b * NCPAD + p];
      }
      ++r;
    }
  }
}

extern "C" void kernel_launch(void* const* d_in, const int* in_sizes, int n_in,
                              void* d_out, int out_size, void* d_ws, size_t ws_size,
                              hipStream_t stream) {
  // setup_inputs dict order: cls0, reg0, cls1, reg1, cls2, reg2, cls3, reg3, anchors
  const float* cls0 = (const float*)d_in[0];
  const float* reg0 = (const float*)d_in[1];
  const float* cls1 = (const float*)d_in[2];
  const float* reg1 = (const float*)d_in[3];
  const float* cls2 = (const float*)d_in[4];
  const float* reg2 = (const float*)d_in[5];
  const float* cls3 = (const float*)d_in[6];
  const float* reg3 = (const float*)d_in[7];
  const float* anchors = (const float*)d_in[8];
  float* out = (float*)d_out;

  char* ws = (char*)d_ws;
  size_t off = 0;
  auto take = [&](size_t bytes) -> void* {
    off = (off + 255) & ~(size_t)255;
    void* p = ws + off;
    off += bytes;
    return p;
  };
  u64* mask      = (u64*)take((size_t)NB * NC * 64 * 8);   // 32.8 MB
  // keybuf (10.2 MB) and tiebuf (2 MB) alias the mask region: they are
  // dead before k_mask writes it (stream-ordered).
  u32* keybuf    = (u32*)mask;
  u32* tiebuf    = (u32*)((char*)mask + (20u << 20));
  u64* cand_key  = (u64*)take((size_t)NB * NCPAD * 8);
  float4* sbox   = (float4*)take((size_t)NB * NCPAD * 16);
  float4* boffA  = (float4*)take((size_t)NB * NCPAD * 16);
  float* area    = (float*)take((size_t)NB * NCPAD * 4);
  float* score   = (float*)take((size_t)NB * NCPAD * 4);
  u64* validmask = (u64*)take((size_t)NB * 64 * 8);
  u32* hist1     = (u32*)take((size_t)64 * 2048 * 4);
  u32* hist2     = (u32*)take((size_t)64 * 2048 * 4);
  u32* hist3     = (u32*)take((size_t)64 * 2048 * 4);
  u64* kth       = (u64*)take((size_t)64 * 8);
  u32* counters  = (u32*)take((size_t)64 * 4);
  u32* tiecnt    = (u32*)take((size_t)64 * 4);
  u32* resolvedf = (u32*)take((size_t)64 * 4);
  u32* state_known = (u32*)take((size_t)64 * 4);
  u32* state_kneed = (u32*)take((size_t)64 * 4);
  (void)ws_size; (void)in_sizes; (void)n_in; (void)out_size;

  k_zero<<<512, 256, 0, stream>>>(out, counters, cand_key, hist1, hist2, hist3,
                                  tiecnt, resolvedf, state_known, state_kneed);
  k_keys<<<192, 1024, 0, stream>>>(cls0, cls1, cls2, cls3, keybuf, hist1);
  k_pick<<<64, 1024, 0, stream>>>(hist1, state_known, state_kneed, resolvedf,
                                  kth, 2048, 21, 0);
  k_hist<<<192, 1024, 0, stream>>>(keybuf, state_known, hist2, 10, 0xFFE00000u,
                                   0x7FFu);
  k_pick<<<64, 1024, 0, stream>>>(hist2, state_known, state_kneed, resolvedf,
                                  kth, 2048, 10, 0);
  k_hist<<<192, 1024, 0, stream>>>(keybuf, state_known, hist3, 0, 0xFFFFFC00u,
                                   0x3FFu);
  k_pick<<<64, 1024, 0, stream>>>(hist3, state_known, state_kneed, resolvedf,
                                  kth, 1024, 0, 1);
  k_tie<<<192, 1024, 0, stream>>>(keybuf, state_known, resolvedf, tiecnt,
                                  tiebuf);
  k_tiepick<<<64, 1024, 0, stream>>>(tiecnt, tiebuf, state_known, state_kneed,
                                     resolvedf, kth);
  k_gather<<<192, 1024, 0, stream>>>(keybuf, kth, reg0, reg1, reg2, reg3,
                                     anchors, counters, cand_key);
  k_sort<<<NB, 1024, 0, stream>>>(cand_key);
  k_decode<<<NB * 4, 1024, 0, stream>>>(cand_key, reg0, reg1, reg2, reg3,
                                        anchors, sbox, boffA, area, score,
                                        validmask);
  k_mask<<<NB * 250, 256, 0, stream>>>(boffA, area, mask);
  k_nms<<<NB, 1024, 0, stream>>>(mask, validmask, sbox, score, out);
}